// Round 4
// baseline (451.621 us; speedup 1.0000x reference)
//
#include <hip/hip_runtime.h>
#include <stdint.h>

typedef __attribute__((ext_vector_type(4))) float f32x4;
typedef __attribute__((ext_vector_type(8))) short s16x8;

struct Params {
  const float* cls_feat[3];
  const float* reg_feat[3];
  const float* obj_w[3];
  const float* obj_b[3];
  const float* cls_w[3];
  const float* cls_b[3];
  const float* reg_w[3];
  const float* reg_b[3];
  float* out;
};

__device__ __forceinline__ unsigned short f2bf(float f) {
  unsigned int u = __builtin_bit_cast(unsigned int, f);
  u = (u + 0x7FFFu + ((u >> 16) & 1u)) >> 16;  // RNE
  return (unsigned short)u;
}

__device__ __forceinline__ s16x8 cvt8(f32x4 a, f32x4 b, bool ok) {
  s16x8 r;
  #pragma unroll
  for (int j = 0; j < 4; ++j) {
    r[j]     = ok ? (short)f2bf(a[j]) : (short)0;
    r[4 + j] = ok ? (short)f2bf(b[j]) : (short)0;
  }
  return r;
}

// async global->LDS, 4 B per lane: LDS dest = uniform base + lane*4,
// global src = per-lane address (pre-rotated for bank-free reads).
__device__ __forceinline__ void gload_lds4(const float* g, float* l) {
  __builtin_amdgcn_global_load_lds(
      (const __attribute__((address_space(1))) unsigned int*)g,
      (__attribute__((address_space(3))) unsigned int*)l, 4, 0, 0);
}

// One block = one (batch, m-tile of 64): runs BOTH cls and reg GEMMs so every
// 596-B output row has a single writer (no cross-block partial-line RMW).
// LDS: fp32 [128 ch][64 m] = 32 KB, K split in 2 halves -> 4 blocks/CU.
// Row c stored rotated by 8*((c>>3)&3) m-slots -> read banks exactly 2-way.
__global__ __launch_bounds__(320, 5) void head_kernel(Params p) {
  const int tid  = threadIdx.x;
  const int lane = tid & 63;
  const int wave = tid >> 6;      // 0..4, one 16-row o-tile each
  const int quad = lane >> 4;     // 0..3
  const int col  = lane & 15;

  // block -> (batch, level, m-tile). 132 tiles/batch: 100 + 25 + 7
  int bx = blockIdx.x;
  int b  = bx / 132;
  int t  = bx - b * 132;
  int level, tloc;
  if (t < 100)      { level = 0; tloc = t; }
  else if (t < 125) { level = 1; tloc = t - 100; }
  else              { level = 2; tloc = t - 125; }

  const int   LW_[3]   = {80, 40, 20};
  const float LS_[3]   = {8.f, 16.f, 32.f};
  const int   LOFF_[3] = {0, 6400, 8000};
  const int   LM_[3]   = {6400, 1600, 400};

  const int   Mlvl = LM_[level];
  const int   Moff = LOFF_[level];
  const float strd = LS_[level];
  const int   m0   = tloc * 64;
  int valid = Mlvl - m0; if (valid > 64) valid = 64;

  __shared__ __align__(16) float lds_f[128 * 64];  // 32768 B

  const size_t outbase = (size_t)b * 8400 + Moff + m0;
  float* out = p.out;
  const int orow    = wave * 16 + col;
  const int o0      = wave * 16 + quad * 4;
  const int rotbase = col + quad * 8;  // read-side rotation base

  for (int ph = 0; ph < 2; ++ph) {
    const bool is_cls = (ph == 0);
    const float* featp = (is_cls ? p.cls_feat[level] : p.reg_feat[level])
                         + (size_t)b * 256 * (size_t)Mlvl + m0;

    const float* wptr;
    bool wvalid = true;
    if (is_cls)          wptr = p.cls_w[level] + orow * 256;
    else if (orow < 64)  wptr = p.reg_w[level] + orow * 256;
    else if (orow == 64) wptr = p.obj_w[level];
    else               { wptr = p.obj_w[level]; wvalid = false; }
    const float* wq = wptr + quad * 8;

    f32x4 bias = {0.f, 0.f, 0.f, 0.f};
    if (is_cls)        bias = *(const f32x4*)(p.cls_b[level] + o0);
    else if (o0 < 64)  bias = *(const f32x4*)(p.reg_b[level] + o0);
    else if (o0 == 64) bias[0] = p.obj_b[level][0];

    f32x4 acc[4];
    #pragma unroll
    for (int mf = 0; mf < 4; ++mf) acc[mf] = (f32x4){0.f, 0.f, 0.f, 0.f};

    #pragma unroll
    for (int h = 0; h < 2; ++h) {
      __syncthreads();  // previous consumers of lds_f are done

      // weights group 0 first (so their wait leaves staging in flight)
      const float* wqh = wq + h * 128;
      f32x4 w0a = *(const f32x4*)(wqh + 0);
      f32x4 w0b = *(const f32x4*)(wqh + 4);
      f32x4 w1a = *(const f32x4*)(wqh + 32);
      f32x4 w1b = *(const f32x4*)(wqh + 36);

      // async stage 128 channel rows (fire-and-forget, no VGPR results)
      for (int r = wave; r < 128; r += 5) {
        const int rot = ((r >> 3) & 3) << 3;
        int mi = (lane - rot) & 63;
        if (mi >= valid) mi = valid - 1;  // partial level-2 tile clamp
        gload_lds4(featp + (size_t)(h * 128 + r) * (size_t)Mlvl + mi,
                   &lds_f[r * 64]);
      }

      s16x8 af0 = cvt8(w0a, w0b, wvalid);   // waits vmcnt(~26), stage flies
      s16x8 af1 = cvt8(w1a, w1b, wvalid);
      f32x4 w2a = *(const f32x4*)(wqh + 64);
      f32x4 w2b = *(const f32x4*)(wqh + 68);
      f32x4 w3a = *(const f32x4*)(wqh + 96);
      f32x4 w3b = *(const f32x4*)(wqh + 100);

      __syncthreads();  // drain staging + barrier

      s16x8 af2 = cvt8(w2a, w2b, wvalid);
      s16x8 af3 = cvt8(w3a, w3b, wvalid);
      s16x8 afr[4] = {af0, af1, af2, af3};

      // GEMM half: D[o][m] += W[o][k] * F[k][m], k in [h*128, h*128+128)
      #pragma unroll
      for (int mf = 0; mf < 4; ++mf) {
        const int rotm = (rotbase + mf * 16) & 63;
        #pragma unroll
        for (int s = 0; s < 4; ++s) {
          const float* bp = &lds_f[(s * 32 + quad * 8) * 64 + rotm];
          s16x8 bf;
          #pragma unroll
          for (int j = 0; j < 8; ++j) bf[j] = (short)f2bf(bp[j * 64]);
          acc[mf] = __builtin_amdgcn_mfma_f32_16x16x32_bf16(afr[s], bf, acc[mf], 0, 0, 0);
        }
      }
    }

    // ---- epilogue ----
    if (is_cls) {
      #pragma unroll
      for (int mf = 0; mf < 4; ++mf) {
        const int m = mf * 16 + col;
        if (m < valid) {
          f32x4 v = acc[mf] + bias;
          float* dst = out + (outbase + m) * 149 + 1 + wave * 16 + quad * 4;
          __builtin_memcpy(dst, &v, 16);
        }
      }
    } else {
      __syncthreads();  // all lds_f reads done; reuse as g_lds [4][64]
      float* g_lds = lds_f;
      if (wave < 4) {
        const float projscale = 16.f / 15.f;
        #pragma unroll
        for (int mf = 0; mf < 4; ++mf) {
          const int m = mf * 16 + col;
          f32x4 v = acc[mf] + bias;
          if (m < valid) {
            float* dst = out + (outbase + m) * 149 + 81 + wave * 16 + quad * 4;
            __builtin_memcpy(dst, &v, 16);
          }
          // softmax over 16 bins: 4 regs x 4 quads (same m column)
          float mx = fmaxf(fmaxf(v[0], v[1]), fmaxf(v[2], v[3]));
          mx = fmaxf(mx, __shfl_xor(mx, 16, 64));
          mx = fmaxf(mx, __shfl_xor(mx, 32, 64));
          const float e0 = __expf(v[0] - mx), e1 = __expf(v[1] - mx);
          const float e2 = __expf(v[2] - mx), e3 = __expf(v[3] - mx);
          float sden = e0 + e1 + e2 + e3;
          const float q4 = (float)(quad * 4);
          float n = q4 * e0 + (q4 + 1.f) * e1 + (q4 + 2.f) * e2 + (q4 + 3.f) * e3;
          sden += __shfl_xor(sden, 16, 64); sden += __shfl_xor(sden, 32, 64);
          n    += __shfl_xor(n, 16, 64);    n    += __shfl_xor(n, 32, 64);
          if (quad == 0) g_lds[wave * 64 + m] = projscale * n / sden;
        }
      } else {
        // wave 4: obj row (o=64 -> quad 0, reg 0)
        #pragma unroll
        for (int mf = 0; mf < 4; ++mf) {
          const int m = mf * 16 + col;
          if (quad == 0 && m < valid)
            out[(outbase + m) * 149] = acc[mf][0] + bias[0];
        }
      }
      __syncthreads();

      // box decode (wave 4): anchors +/- expectation * stride, m = lane
      if (wave == 4 && lane < valid) {
        const int m = lane;
        const float g0 = g_lds[m],       g1 = g_lds[64 + m];
        const float g2 = g_lds[128 + m], g3 = g_lds[192 + m];
        const int mg = m0 + m;
        int hh;
        if (level == 0)      hh = mg / 80;
        else if (level == 1) hh = mg / 40;
        else                 hh = mg / 20;
        const int ww = mg - hh * LW_[level];
        const float ax = (ww + 0.5f) * strd;
        const float ay = (hh + 0.5f) * strd;
        f32x4 bv;
        bv[0] = ax - g0 * strd; bv[1] = ay - g1 * strd;
        bv[2] = ax + g2 * strd; bv[3] = ay + g3 * strd;
        float* dst = out + (outbase + m) * 149 + 145;
        __builtin_memcpy(dst, &bv, 16);
      }
    }
  }
}

extern "C" void kernel_launch(void* const* d_in, const int* in_sizes, int n_in,
                              void* d_out, int out_size, void* d_ws, size_t ws_size,
                              hipStream_t stream) {
  (void)in_sizes; (void)n_in; (void)out_size; (void)d_ws; (void)ws_size;
  Params p;
  p.cls_feat[0] = (const float*)d_in[0];
  p.reg_feat[0] = (const float*)d_in[1];
  p.cls_feat[1] = (const float*)d_in[2];
  p.reg_feat[1] = (const float*)d_in[3];
  p.cls_feat[2] = (const float*)d_in[4];
  p.reg_feat[2] = (const float*)d_in[5];
  for (int l = 0; l < 3; ++l) {
    const int base = 6 + l * 6;
    p.obj_w[l] = (const float*)d_in[base + 0];
    p.obj_b[l] = (const float*)d_in[base + 1];
    p.cls_w[l] = (const float*)d_in[base + 2];
    p.cls_b[l] = (const float*)d_in[base + 3];
    p.reg_w[l] = (const float*)d_in[base + 4];
    p.reg_b[l] = (const float*)d_in[base + 5];
  }
  p.out = (float*)d_out;

  dim3 grid(16 * 132);  // batch * m-tiles (100+25+7); both GEMMs per block
  dim3 block(320);      // 5 waves, one 16-row o-tile each
  hipLaunchKernelGGL(head_kernel, grid, block, 0, stream, p);
}